// Round 3
// baseline (289.077 us; speedup 1.0000x reference)
//
#include <hip/hip_runtime.h>

typedef _Float16 f16;
typedef __attribute__((ext_vector_type(8))) _Float16 f16x8;
typedef __attribute__((ext_vector_type(4))) float f32x4;

#define ND 256
#define OD 256

// ws layout: rs int[ng+1] | pad to 256B | W2 f16[32][256][8] (128 KB)

__global__ void k_rowstarts(const int* __restrict__ b32, int N, int ng, int* __restrict__ rs) {
    __shared__ int s_is64;
    if (threadIdx.x == 0) {
        // Sniff dtype: int64 batch has zero high words.
        int m = (N / 2) & ~1;
        bool oz = true;
        for (int j = 0; j < 8; ++j) oz &= (b32[m + 2*j + 1] == 0);
        s_is64 = oz ? 1 : 0;
    }
    __syncthreads();
    const bool is64 = (s_is64 != 0);
    int g = blockIdx.x * blockDim.x + threadIdx.x;
    if (g > ng) return;
    int lo = 0, hi = N;
    while (lo < hi) {
        int mid = (lo + hi) >> 1;
        int v = is64 ? b32[2*mid] : b32[mid];
        if (v < g) lo = mid + 1; else hi = mid;
    }
    rs[g] = lo;
}

// Repack value_w [k][j] -> W2 [k/8][j][k%8] as f16 (B-frag = 16 contiguous bytes).
__global__ void k_wpack(const float* __restrict__ W, f16* __restrict__ W2) {
    const int kb = blockIdx.x;      // 0..31
    const int j  = threadIdx.x;     // 0..255
    f16x8 v;
    #pragma unroll
    for (int e = 0; e < 8; ++e)
        v[e] = (f16)W[(size_t)(kb * 8 + e) * OD + j];
    *(f16x8*)(W2 + (size_t)kb * 2048 + j * 8) = v;
}

// Issue one 16-row chunk of x into a named register bank (plain arrays,
// compile-time indices after unroll: stays in VGPRs; no address capture).
#define ISSUE_CHUNK(RA, RB, ROW)                                             \
    {                                                                        \
        const int r_ = (ROW);                                                \
        const bool v_ = r_ < segN;                                           \
        const float* xp_ = x + (size_t)(seg0 + r_) * ND + h * 8;             \
        _Pragma("unroll")                                                    \
        for (int ks = 0; ks < 8; ++ks) {                                     \
            if (v_) {                                                        \
                RA[ks] = *(const float4*)(xp_ + ks * 32);                    \
                RB[ks] = *(const float4*)(xp_ + ks * 32 + 4);                \
            } else {                                                         \
                RA[ks] = f4z; RB[ks] = f4z;                                  \
            }                                                                \
        }                                                                    \
    }

// Consume a bank: gate partial dot (f32) + convert to f16 A-fragments.
#define CONSUME_CHUNK(RA, RB, AV, GP)                                        \
    {                                                                        \
        float g1_ = 0.f, g2_ = 0.f;                                          \
        _Pragma("unroll")                                                    \
        for (int ks = 0; ks < 8; ++ks) {                                     \
            const float4 a = RA[ks], b = RB[ks];                             \
            const float4 wa = *(const float4*)(gwl + ks * 32 + h * 8);       \
            const float4 wb = *(const float4*)(gwl + ks * 32 + h * 8 + 4);   \
            g1_ += (a.x*wa.x + a.y*wa.y) + (a.z*wa.z + a.w*wa.w);            \
            g2_ += (b.x*wb.x + b.y*wb.y) + (b.z*wb.z + b.w*wb.w);            \
            AV[ks][0] = (f16)a.x; AV[ks][1] = (f16)a.y;                      \
            AV[ks][2] = (f16)a.z; AV[ks][3] = (f16)a.w;                      \
            AV[ks][4] = (f16)b.x; AV[ks][5] = (f16)b.y;                      \
            AV[ks][6] = (f16)b.z; AV[ks][7] = (f16)b.w;                      \
        }                                                                    \
        GP = g1_ + g2_;                                                      \
    }

// LDS (128 KB) caps at 1 block/CU = 2 waves/SIMD regardless of VGPRs.
// Tell the allocator exactly that, so it grants the full 256-VGPR budget
// (live set across the cs loop is ~200: dual banks + A-frags + acc).
__global__ __attribute__((amdgpu_flat_work_group_size(512, 512),
                          amdgpu_waves_per_eu(2, 2)))
void k_main(const float* __restrict__ x, const int* __restrict__ rs,
            const float* __restrict__ gate_w, const float* __restrict__ gate_b,
            const f16* __restrict__ W2, const float* __restrict__ value_b,
            float* __restrict__ zout, float* __restrict__ attn, int ng) {
    __shared__ __align__(16) f16 Bl[32 * 256 * 8];   // 128 KB, [kb][col][8]
    __shared__ float gwl[ND];
    __shared__ float vbl[OD];

    const int tid = threadIdx.x;    // 0..511
    const int wid = tid >> 6;       // 0..7
    const int lane = tid & 63;
    const int rowl = lane & 15;
    const int h = lane >> 4;

    // one-time: B -> LDS (coalesced linear), gate_w / value_b -> LDS
    #pragma unroll
    for (int i = 0; i < 16; ++i) {
        const int f = i * 512 + tid;
        *(f16x8*)((char*)Bl + (size_t)f * 16) = *(const f16x8*)(W2 + (size_t)f * 8);
    }
    if (tid < ND) gwl[tid] = gate_w[tid];
    else if (tid < ND + OD) vbl[tid - ND] = value_b[tid - ND];
    __syncthreads();   // ONLY block barrier

    const float gb = gate_b[0];
    const float4 f4z = make_float4(0.f, 0.f, 0.f, 0.f);

    #pragma unroll 1
    for (int gq = 0; gq < 2; ++gq) {
        const int g = blockIdx.x * 16 + gq * 8 + wid;   // wave-uniform
        if (g >= ng) continue;
        const int seg0 = rs[g], seg1 = rs[g + 1];
        const int segN = seg1 - seg0;

        float S = 0.f;                                  // per-lane partial (h==0 masked)
        float zs[16];
        #pragma unroll
        for (int cs = 0; cs < 16; ++cs) zs[cs] = 0.f;

        const int nmt = (segN + 31) >> 5;   // 32-row macro-tiles

        // Pipeline: LO bank (ra/rb) is prefetched across the cs loop;
        // HI bank (rc/rd) is issued at tile top, consumed after consume-LO.
        float4 ra[8], rb[8];      // LO / next-LO prefetch bank
        float4 rc[8], rd[8];      // HI bank (transient)
        f16x8 avlo[8], avhi[8];

        if (nmt > 0) ISSUE_CHUNK(ra, rb, rowl);   // prologue: LO of tile 0

        #pragma unroll 1
        for (int mt = 0; mt < nmt; ++mt) {
            const int row_lo = mt * 32 + rowl;
            const bool v_lo = row_lo < segN;
            const bool v_hi = row_lo + 16 < segN;

            // issue HI first: consume-LO's VALU covers part of its latency
            ISSUE_CHUNK(rc, rd, mt * 32 + 16 + rowl);

            // consume LO (loads issued before previous cs loop: ~no stall)
            float gplo, gphi;
            CONSUME_CHUNK(ra, rb, avlo, gplo);

            // LO gate reduce + exp, still in HI's load shadow
            gplo += __shfl_xor(gplo, 16, 64);
            gplo += __shfl_xor(gplo, 32, 64);
            const float wlo = v_lo ? __expf(fminf(gplo + gb, 60.f)) : 0.f;
            if (h == 0 && v_lo) attn[seg0 + row_lo] = wlo;   // stash exp(g)

            // consume HI
            CONSUME_CHUNK(rc, rd, avhi, gphi);

            // issue next tile's LO; the cs loop (~2.5k cyc) covers its latency
            if (mt + 1 < nmt) ISSUE_CHUNK(ra, rb, (mt + 1) * 32 + rowl);
            __builtin_amdgcn_sched_barrier(0);   // pin prefetch issue above

            gphi += __shfl_xor(gphi, 16, 64);
            gphi += __shfl_xor(gphi, 32, 64);
            const float whi = v_hi ? __expf(fminf(gphi + gb, 60.f)) : 0.f;
            if (h == 0 && v_hi) attn[seg0 + row_lo + 16] = whi;

            S += (h == 0) ? (wlo + whi) : 0.f;              // deferred reduction
            const float w0 = __shfl(wlo, h * 4 + 0, 64);
            const float w1 = __shfl(wlo, h * 4 + 1, 64);
            const float w2 = __shfl(wlo, h * 4 + 2, 64);
            const float w3 = __shfl(wlo, h * 4 + 3, 64);
            const float w4 = __shfl(whi, h * 4 + 0, 64);
            const float w5 = __shfl(whi, h * 4 + 1, 64);
            const float w6 = __shfl(whi, h * 4 + 2, 64);
            const float w7 = __shfl(whi, h * 4 + 3, 64);

            // 16 col-slices: 8 B-frag reads each, EACH feeding 2 MFMAs (lo+hi).
            #pragma unroll 2
            for (int cs = 0; cs < 16; ++cs) {
                f32x4 alo = {0.f, 0.f, 0.f, 0.f}, ahi = {0.f, 0.f, 0.f, 0.f};
                const char* bb = (const char*)Bl + h * 4096 + (size_t)(cs * 16 + rowl) * 16;
                #pragma unroll
                for (int ks = 0; ks < 8; ++ks) {
                    const f16x8 bf = *(const f16x8*)(bb + ks * 16384);
                    alo = __builtin_amdgcn_mfma_f32_16x16x32_f16(avlo[ks], bf, alo, 0, 0, 0);
                    ahi = __builtin_amdgcn_mfma_f32_16x16x32_f16(avhi[ks], bf, ahi, 0, 0, 0);
                }
                const float vbv = vbl[cs * 16 + rowl];
                float p0 = alo[0] + vbv, p1 = alo[1] + vbv;
                float p2 = alo[2] + vbv, p3 = alo[3] + vbv;
                zs[cs] += w0 * p0 * __builtin_amdgcn_rcpf(1.f + __expf(-p0))
                        + w1 * p1 * __builtin_amdgcn_rcpf(1.f + __expf(-p1))
                        + w2 * p2 * __builtin_amdgcn_rcpf(1.f + __expf(-p2))
                        + w3 * p3 * __builtin_amdgcn_rcpf(1.f + __expf(-p3));
                p0 = ahi[0] + vbv; p1 = ahi[1] + vbv;
                p2 = ahi[2] + vbv; p3 = ahi[3] + vbv;
                zs[cs] += w4 * p0 * __builtin_amdgcn_rcpf(1.f + __expf(-p0))
                        + w5 * p1 * __builtin_amdgcn_rcpf(1.f + __expf(-p1))
                        + w6 * p2 * __builtin_amdgcn_rcpf(1.f + __expf(-p2))
                        + w7 * p3 * __builtin_amdgcn_rcpf(1.f + __expf(-p3));
            }
        }

        // graph end: single S butterfly (h!=0 lanes hold 0 partials)
        #pragma unroll
        for (int off = 32; off >= 1; off >>= 1) S += __shfl_xor(S, off, 64);

        const float inv = __builtin_amdgcn_rcpf(S + 1e-8f);
        #pragma unroll
        for (int cs = 0; cs < 16; ++cs) {
            float v = zs[cs];
            v += __shfl_xor(v, 16, 64);
            v += __shfl_xor(v, 32, 64);
            if (lane < 16) zout[(size_t)g * OD + cs * 16 + lane] = v * inv;
        }
        asm volatile("s_waitcnt vmcnt(0)" ::: "memory");   // exp(g) stores visible
        for (int i = seg0 + lane; i < seg1; i += 64)
            attn[i] = attn[i] * inv;                        // pure scale
    }
}

extern "C" void kernel_launch(void* const* d_in, const int* in_sizes, int n_in,
                              void* d_out, int out_size, void* d_ws, size_t ws_size,
                              hipStream_t stream) {
    const float* x       = (const float*)d_in[0];
    const int*   batch   = (const int*)d_in[1];
    const float* gate_w  = (const float*)d_in[3];
    const float* gate_b  = (const float*)d_in[4];
    const float* value_w = (const float*)d_in[5];
    const float* value_b = (const float*)d_in[6];

    const int N  = in_sizes[1];
    const int ng = (out_size - N) / OD;

    int* rs = (int*)d_ws;
    f16* W2 = (f16*)(((uintptr_t)(rs + ng + 1) + 255) & ~(uintptr_t)255);

    k_rowstarts<<<(ng + 1 + 255) / 256, 256, 0, stream>>>(batch, N, ng, rs);
    k_wpack<<<32, 256, 0, stream>>>(value_w, W2);

    float* zout = (float*)d_out;
    float* attn = zout + (size_t)ng * OD;

    k_main<<<(ng + 15) / 16, 512, 0, stream>>>(x, rs, gate_w, gate_b, W2, value_b,
                                               zout, attn, ng);
}

// Round 4
// 159.403 us; speedup vs baseline: 1.8135x; 1.8135x over previous
//
#include <hip/hip_runtime.h>

typedef _Float16 f16;
typedef __attribute__((ext_vector_type(8))) _Float16 f16x8;
typedef __attribute__((ext_vector_type(4))) float f32x4;

#define ND 256
#define OD 256

// ws layout: rs int[ng+1] | pad to 256B | W2 f16[32][256][8] (128 KB)

__global__ void k_rowstarts(const int* __restrict__ b32, int N, int ng, int* __restrict__ rs) {
    __shared__ int s_is64;
    if (threadIdx.x == 0) {
        // Sniff dtype: int64 batch has zero high words.
        int m = (N / 2) & ~1;
        bool oz = true;
        for (int j = 0; j < 8; ++j) oz &= (b32[m + 2*j + 1] == 0);
        s_is64 = oz ? 1 : 0;
    }
    __syncthreads();
    const bool is64 = (s_is64 != 0);
    int g = blockIdx.x * blockDim.x + threadIdx.x;
    if (g > ng) return;
    int lo = 0, hi = N;
    while (lo < hi) {
        int mid = (lo + hi) >> 1;
        int v = is64 ? b32[2*mid] : b32[mid];
        if (v < g) lo = mid + 1; else hi = mid;
    }
    rs[g] = lo;
}

// Repack value_w [k][j] -> W2 [k/8][j][k%8] as f16 (B-frag = 16 contiguous bytes).
__global__ void k_wpack(const float* __restrict__ W, f16* __restrict__ W2) {
    const int kb = blockIdx.x;      // 0..31
    const int j  = threadIdx.x;     // 0..255
    f16x8 v;
    #pragma unroll
    for (int e = 0; e < 8; ++e)
        v[e] = (f16)W[(size_t)(kb * 8 + e) * OD + j];
    *(f16x8*)(W2 + (size_t)kb * 2048 + j * 8) = v;
}

// Issue one 16-row chunk of x into a named register bank (plain arrays,
// compile-time indices after unroll: stays in VGPRs; no address capture).
#define ISSUE_CHUNK(RA, RB, ROW)                                             \
    {                                                                        \
        const int r_ = (ROW);                                                \
        const bool v_ = r_ < segN;                                           \
        const float* xp_ = x + (size_t)(seg0 + r_) * ND + h * 8;             \
        _Pragma("unroll")                                                    \
        for (int ks = 0; ks < 8; ++ks) {                                     \
            if (v_) {                                                        \
                RA[ks] = *(const float4*)(xp_ + ks * 32);                    \
                RB[ks] = *(const float4*)(xp_ + ks * 32 + 4);                \
            } else {                                                         \
                RA[ks] = f4z; RB[ks] = f4z;                                  \
            }                                                                \
        }                                                                    \
    }

// Consume a bank: gate partial dot (f32) + convert to f16 A-fragments.
#define CONSUME_CHUNK(RA, RB, AV, GP)                                        \
    {                                                                        \
        float g1_ = 0.f, g2_ = 0.f;                                          \
        _Pragma("unroll")                                                    \
        for (int ks = 0; ks < 8; ++ks) {                                     \
            const float4 a = RA[ks], b = RB[ks];                             \
            const float4 wa = *(const float4*)(gwl + ks * 32 + h * 8);       \
            const float4 wb = *(const float4*)(gwl + ks * 32 + h * 8 + 4);   \
            g1_ += (a.x*wa.x + a.y*wa.y) + (a.z*wa.z + a.w*wa.w);            \
            g2_ += (b.x*wb.x + b.y*wb.y) + (b.z*wb.z + b.w*wb.w);            \
            AV[ks][0] = (f16)a.x; AV[ks][1] = (f16)a.y;                      \
            AV[ks][2] = (f16)a.z; AV[ks][3] = (f16)a.w;                      \
            AV[ks][4] = (f16)b.x; AV[ks][5] = (f16)b.y;                      \
            AV[ks][6] = (f16)b.z; AV[ks][7] = (f16)b.w;                      \
        }                                                                    \
        GP = g1_ + g2_;                                                      \
    }

// LDS (128 KB) -> 1 block/CU = 2 waves/SIMD. min-2-waves/EU pins the
// 256-VGPR budget (peak demand ~200: no bank crosses the cs loop).
__global__ __launch_bounds__(512, 2)
void k_main(const float* __restrict__ x, const int* __restrict__ rs,
            const float* __restrict__ gate_w, const float* __restrict__ gate_b,
            const f16* __restrict__ W2, const float* __restrict__ value_b,
            float* __restrict__ zout, float* __restrict__ attn, int ng) {
    __shared__ __align__(16) f16 Bl[32 * 256 * 8];   // 128 KB, [kb][col][8]
    __shared__ float gwl[ND];
    __shared__ float vbl[OD];

    const int tid = threadIdx.x;    // 0..511
    const int wid = tid >> 6;       // 0..7
    const int lane = tid & 63;
    const int rowl = lane & 15;
    const int h = lane >> 4;

    // one-time: B -> LDS (coalesced linear), gate_w / value_b -> LDS
    #pragma unroll
    for (int i = 0; i < 16; ++i) {
        const int f = i * 512 + tid;
        *(f16x8*)((char*)Bl + (size_t)f * 16) = *(const f16x8*)(W2 + (size_t)f * 8);
    }
    if (tid < ND) gwl[tid] = gate_w[tid];
    else if (tid < ND + OD) vbl[tid - ND] = value_b[tid - ND];
    __syncthreads();   // ONLY block barrier

    // Anti-phase the two waves sharing each SIMD: odd waves sleep ~13 kcy
    // once, so thereafter one wave's load phase overlaps the other's compute.
    if (wid & 1) {
        __builtin_amdgcn_s_sleep(100);
        __builtin_amdgcn_s_sleep(100);
    }

    const float gb = gate_b[0];
    const float4 f4z = make_float4(0.f, 0.f, 0.f, 0.f);

    #pragma unroll 1
    for (int gq = 0; gq < 2; ++gq) {
        const int g = blockIdx.x * 16 + gq * 8 + wid;   // wave-uniform
        if (g >= ng) continue;
        const int seg0 = rs[g], seg1 = rs[g + 1];
        const int segN = seg1 - seg0;

        float S = 0.f;                                  // per-lane partial (h==0 masked)
        float zs[16];
        #pragma unroll
        for (int cs = 0; cs < 16; ++cs) zs[cs] = 0.f;

        const int nmt = (segN + 31) >> 5;   // 32-row macro-tiles

        #pragma unroll 1
        for (int mt = 0; mt < nmt; ++mt) {
            const int row_lo = mt * 32 + rowl;
            const bool v_lo = row_lo < segN;
            const bool v_hi = row_lo + 16 < segN;

            // Issue the WHOLE 32-row tile (32 KB/wave outstanding), then
            // consume lo at vmcnt(16) while hi is still in flight.
            float4 ra[8], rb[8];      // lo bank
            float4 rc[8], rd[8];      // hi bank
            ISSUE_CHUNK(ra, rb, row_lo);
            ISSUE_CHUNK(rc, rd, mt * 32 + 16 + rowl);

            __builtin_amdgcn_s_setprio(1);   // compute phase: keep SIMD

            float gplo, gphi;
            f16x8 avlo[8], avhi[8];
            CONSUME_CHUNK(ra, rb, avlo, gplo);

            // lo gate reduce + exp in hi's load shadow
            gplo += __shfl_xor(gplo, 16, 64);
            gplo += __shfl_xor(gplo, 32, 64);
            const float wlo = v_lo ? __expf(fminf(gplo + gb, 60.f)) : 0.f;
            if (h == 0 && v_lo) attn[seg0 + row_lo] = wlo;   // stash exp(g)

            CONSUME_CHUNK(rc, rd, avhi, gphi);

            gphi += __shfl_xor(gphi, 16, 64);
            gphi += __shfl_xor(gphi, 32, 64);
            const float whi = v_hi ? __expf(fminf(gphi + gb, 60.f)) : 0.f;
            if (h == 0 && v_hi) attn[seg0 + row_lo + 16] = whi;

            S += (h == 0) ? (wlo + whi) : 0.f;              // deferred reduction
            const float w0 = __shfl(wlo, h * 4 + 0, 64);
            const float w1 = __shfl(wlo, h * 4 + 1, 64);
            const float w2 = __shfl(wlo, h * 4 + 2, 64);
            const float w3 = __shfl(wlo, h * 4 + 3, 64);
            const float w4 = __shfl(whi, h * 4 + 0, 64);
            const float w5 = __shfl(whi, h * 4 + 1, 64);
            const float w6 = __shfl(whi, h * 4 + 2, 64);
            const float w7 = __shfl(whi, h * 4 + 3, 64);

            // 16 col-slices: 8 B-frag reads each, EACH feeding 2 MFMAs (lo+hi).
            #pragma unroll 2
            for (int cs = 0; cs < 16; ++cs) {
                f32x4 alo = {0.f, 0.f, 0.f, 0.f}, ahi = {0.f, 0.f, 0.f, 0.f};
                const char* bb = (const char*)Bl + h * 4096 + (size_t)(cs * 16 + rowl) * 16;
                #pragma unroll
                for (int ks = 0; ks < 8; ++ks) {
                    const f16x8 bf = *(const f16x8*)(bb + ks * 16384);
                    alo = __builtin_amdgcn_mfma_f32_16x16x32_f16(avlo[ks], bf, alo, 0, 0, 0);
                    ahi = __builtin_amdgcn_mfma_f32_16x16x32_f16(avhi[ks], bf, ahi, 0, 0, 0);
                }
                const float vbv = vbl[cs * 16 + rowl];
                float p0 = alo[0] + vbv, p1 = alo[1] + vbv;
                float p2 = alo[2] + vbv, p3 = alo[3] + vbv;
                zs[cs] += w0 * p0 * __builtin_amdgcn_rcpf(1.f + __expf(-p0))
                        + w1 * p1 * __builtin_amdgcn_rcpf(1.f + __expf(-p1))
                        + w2 * p2 * __builtin_amdgcn_rcpf(1.f + __expf(-p2))
                        + w3 * p3 * __builtin_amdgcn_rcpf(1.f + __expf(-p3));
                p0 = ahi[0] + vbv; p1 = ahi[1] + vbv;
                p2 = ahi[2] + vbv; p3 = ahi[3] + vbv;
                zs[cs] += w4 * p0 * __builtin_amdgcn_rcpf(1.f + __expf(-p0))
                        + w5 * p1 * __builtin_amdgcn_rcpf(1.f + __expf(-p1))
                        + w6 * p2 * __builtin_amdgcn_rcpf(1.f + __expf(-p2))
                        + w7 * p3 * __builtin_amdgcn_rcpf(1.f + __expf(-p3));
            }

            __builtin_amdgcn_s_setprio(0);   // load phase next
        }

        // graph end: single S butterfly (h!=0 lanes hold 0 partials)
        #pragma unroll
        for (int off = 32; off >= 1; off >>= 1) S += __shfl_xor(S, off, 64);

        const float inv = __builtin_amdgcn_rcpf(S + 1e-8f);
        #pragma unroll
        for (int cs = 0; cs < 16; ++cs) {
            float v = zs[cs];
            v += __shfl_xor(v, 16, 64);
            v += __shfl_xor(v, 32, 64);
            if (lane < 16) zout[(size_t)g * OD + cs * 16 + lane] = v * inv;
        }
        asm volatile("s_waitcnt vmcnt(0)" ::: "memory");   // exp(g) stores visible
        for (int i = seg0 + lane; i < seg1; i += 64)
            attn[i] = attn[i] * inv;                        // pure scale
    }
}

extern "C" void kernel_launch(void* const* d_in, const int* in_sizes, int n_in,
                              void* d_out, int out_size, void* d_ws, size_t ws_size,
                              hipStream_t stream) {
    const float* x       = (const float*)d_in[0];
    const int*   batch   = (const int*)d_in[1];
    const float* gate_w  = (const float*)d_in[3];
    const float* gate_b  = (const float*)d_in[4];
    const float* value_w = (const float*)d_in[5];
    const float* value_b = (const float*)d_in[6];

    const int N  = in_sizes[1];
    const int ng = (out_size - N) / OD;

    int* rs = (int*)d_ws;
    f16* W2 = (f16*)(((uintptr_t)(rs + ng + 1) + 255) & ~(uintptr_t)255);

    k_rowstarts<<<(ng + 1 + 255) / 256, 256, 0, stream>>>(batch, N, ng, rs);
    k_wpack<<<32, 256, 0, stream>>>(value_w, W2);

    float* zout = (float*)d_out;
    float* attn = zout + (size_t)ng * OD;

    k_main<<<(ng + 15) / 16, 512, 0, stream>>>(x, rs, gate_w, gate_b, W2, value_b,
                                               zout, attn, ng);
}